// Round 5
// baseline (830.654 us; speedup 1.0000x reference)
//
#include <hip/hip_runtime.h>
#include <hip/hip_bf16.h>

typedef __attribute__((ext_vector_type(8))) short short8;
typedef __attribute__((ext_vector_type(4))) short short4_t;
typedef __attribute__((ext_vector_type(4))) float f32x4;

constexpr int MBS = 16, HD = 64, NMB = 256;

#define MFMA32(a, b, c) __builtin_amdgcn_mfma_f32_16x16x32_bf16(a, b, c, 0, 0, 0)
#define TR_READ(dst, addr, IMM) \
    asm volatile("ds_read_b64_tr_b16 %0, %1 offset:" IMM : "=&v"(dst) : "v"(addr) : "memory")

union U4S8 { unsigned u[4]; short8 s; };
union U2S4 { unsigned u[2]; short4_t s; };

__device__ inline unsigned pkbf(float a, float b) {
    union { __hip_bfloat162 h; unsigned u; } c;
    c.h = __float22bfloat162_rn(make_float2(a, b));
    return c.u;
}
__device__ inline short8 cmb(short4_t a, short4_t b) {
    short8 r;
    r[0]=a[0]; r[1]=a[1]; r[2]=a[2]; r[3]=a[3];
    r[4]=b[0]; r[5]=b[1]; r[6]=b[2]; r[7]=b[3];
    return r;
}

__global__ __launch_bounds__(64) void ttt_scan(
    const float* __restrict__ gXQ, const float* __restrict__ gXK,
    const float* __restrict__ gXV, const float* __restrict__ gETA,
    const float* __restrict__ gW1, const float* __restrict__ gB1,
    const float* __restrict__ gLNW, const float* __restrict__ gLNB,
    float* __restrict__ gOUT)
{
    __shared__ __align__(16) short sWt[64 * 72];   // W^T [n][k] bf16
    __shared__ __align__(16) short sGt[2048];      // g tiled; jblk 4..7 permanently 0
    __shared__ __align__(16) short sXKe[2048];     // -le*xk tiled; hi jblks 0
    __shared__ __align__(16) float sZ1[16 * 68];
    __shared__ __align__(16) float sZb[16 * 68];
    __shared__ __align__(16) float sAttn[16 * 20];

    const int l  = threadIdx.x;
    const int gq = l >> 4, lc = l & 15;   // frag-layout coords
    const int s  = l >> 2, q  = l & 3;    // row-layout coords (4 lanes/row)
    const int bh = blockIdx.x, b = bh >> 3, h = bh & 7;

    const float* xqg = gXQ + (size_t)bh * (NMB * MBS * HD);
    const float* xkg = gXK + (size_t)bh * (NMB * MBS * HD);
    const float* xvg = gXV + (size_t)bh * (NMB * MBS * HD);
    const float* etg = gETA + (size_t)bh * (NMB * MBS * MBS);

    // zero the permanently-zero hi-jblk regions (k=16..31 of the K=32 frags)
    for (int i = l; i < 512; i += 64) {
        ((unsigned*)sGt)[512 + i] = 0;
        ((unsigned*)sXKe)[512 + i] = 0;
    }

    // ---- W state: 16 C-fragments; bf16 mirror in sWt ----
    f32x4 Wacc[4][4];
#pragma unroll
    for (int mi = 0; mi < 4; ++mi)
#pragma unroll
        for (int ni = 0; ni < 4; ++ni) {
#pragma unroll
            for (int r = 0; r < 4; ++r)
                Wacc[mi][ni][r] = gW1[h * 4096 + (16 * mi + 4 * gq + r) * 64 + 16 * ni + lc];
            U2S4 wp;
            wp.u[0] = pkbf(Wacc[mi][ni][0], Wacc[mi][ni][1]);
            wp.u[1] = pkbf(Wacc[mi][ni][2], Wacc[mi][ni][3]);
            *(short4_t*)&sWt[(16 * ni + lc) * 72 + 16 * mi + 4 * gq] = wp.s;
        }
    f32x4 b1v;
#pragma unroll
    for (int ni = 0; ni < 4; ++ni) b1v[ni] = gB1[h * 64 + 16 * ni + lc];

    // ---- LN params in row layout (lane owns cols 16q..16q+15) ----
    f32x4 gam4[4], bet4[4];
#pragma unroll
    for (int c4 = 0; c4 < 4; ++c4) {
        gam4[c4] = *(const f32x4*)&gLNW[h * 64 + 16 * q + 4 * c4];
        bet4[c4] = *(const f32x4*)&gLNB[h * 64 + 16 * q + 4 * c4];
    }
    float sc1 = 0.f;
#pragma unroll
    for (int c4 = 0; c4 < 4; ++c4)
#pragma unroll
        for (int c = 0; c < 4; ++c) sc1 = fmaf(gam4[c4][c], gam4[c4][c], sc1);
    sc1 += __shfl_xor(sc1, 1);
    sc1 += __shfl_xor(sc1, 2);

    const int ecol = (gq < 2) ? 8 * gq : 0;   // clamped eta/attn column base

    // ---- prefetch step 0 ----
    f32x4 fk0 = *(const f32x4*)&xkg[lc * 64 + 8 * gq];
    f32x4 fk1 = *(const f32x4*)&xkg[lc * 64 + 8 * gq + 4];
    f32x4 fk2 = *(const f32x4*)&xkg[lc * 64 + 32 + 8 * gq];
    f32x4 fk3 = *(const f32x4*)&xkg[lc * 64 + 32 + 8 * gq + 4];
    f32x4 fq0 = *(const f32x4*)&xqg[lc * 64 + 8 * gq];
    f32x4 fq1 = *(const f32x4*)&xqg[lc * 64 + 8 * gq + 4];
    f32x4 fq2 = *(const f32x4*)&xqg[lc * 64 + 32 + 8 * gq];
    f32x4 fq3 = *(const f32x4*)&xqg[lc * 64 + 32 + 8 * gq + 4];
    f32x4 fv[4];
#pragma unroll
    for (int c4 = 0; c4 < 4; ++c4) fv[c4] = *(const f32x4*)&xvg[s * 64 + 16 * q + 4 * c4];
    f32x4 ea0 = *(const f32x4*)&etg[lc * 16 + ecol];
    f32x4 ea1 = *(const f32x4*)&etg[lc * 16 + ecol + 4];
    f32x4 le0 = *(const f32x4*)&etg[240 + ecol];
    f32x4 le1 = *(const f32x4*)&etg[240 + ecol + 4];
    float lesv = etg[240 + s];

#pragma unroll 1
    for (int m = 0; m < NMB; ++m) {
        // ======== build A-frags from prefetched xk/xq ========
        U4S8 ak0, ak1, aq0, aq1;
        ak0.u[0] = pkbf(fk0[0], fk0[1]); ak0.u[1] = pkbf(fk0[2], fk0[3]);
        ak0.u[2] = pkbf(fk1[0], fk1[1]); ak0.u[3] = pkbf(fk1[2], fk1[3]);
        ak1.u[0] = pkbf(fk2[0], fk2[1]); ak1.u[1] = pkbf(fk2[2], fk2[3]);
        ak1.u[2] = pkbf(fk3[0], fk3[1]); ak1.u[3] = pkbf(fk3[2], fk3[3]);
        aq0.u[0] = pkbf(fq0[0], fq0[1]); aq0.u[1] = pkbf(fq0[2], fq0[3]);
        aq0.u[2] = pkbf(fq1[0], fq1[1]); aq0.u[3] = pkbf(fq1[2], fq1[3]);
        aq1.u[0] = pkbf(fq2[0], fq2[1]); aq1.u[1] = pkbf(fq2[2], fq2[3]);
        aq1.u[2] = pkbf(fq3[0], fq3[1]); aq1.u[3] = pkbf(fq3[2], fq3[3]);

        // reissue xk/xq frag prefetch for m+1 (in flight all step)
        if (m + 1 < NMB) {
            const size_t o = (size_t)(m + 1) * 1024;
            fk0 = *(const f32x4*)&xkg[o + lc * 64 + 8 * gq];
            fk1 = *(const f32x4*)&xkg[o + lc * 64 + 8 * gq + 4];
            fk2 = *(const f32x4*)&xkg[o + lc * 64 + 32 + 8 * gq];
            fk3 = *(const f32x4*)&xkg[o + lc * 64 + 32 + 8 * gq + 4];
            fq0 = *(const f32x4*)&xqg[o + lc * 64 + 8 * gq];
            fq1 = *(const f32x4*)&xqg[o + lc * 64 + 8 * gq + 4];
            fq2 = *(const f32x4*)&xqg[o + lc * 64 + 32 + 8 * gq];
            fq3 = *(const f32x4*)&xqg[o + lc * 64 + 32 + 8 * gq + 4];
        }

        // current-step row loads (cache lines already touched by frag prefetch)
        f32x4 rq[4], rk[4];
#pragma unroll
        for (int c4 = 0; c4 < 4; ++c4) {
            rq[c4] = *(const f32x4*)&xqg[(size_t)m * 1024 + s * 64 + 16 * q + 4 * c4];
            rk[c4] = *(const f32x4*)&xkg[(size_t)m * 1024 + s * 64 + 16 * q + 4 * c4];
        }

        // ======== MFMA1: Z1 = xk@W + b1 ; Zq = xq@W + b1 ; Attn ========
        f32x4 z1a[4], zqa[4];
#pragma unroll
        for (int ni = 0; ni < 4; ++ni) {
            const short8 bw0 = *(const short8*)&sWt[(16 * ni + lc) * 72 + 8 * gq];
            const short8 bw1 = *(const short8*)&sWt[(16 * ni + lc) * 72 + 32 + 8 * gq];
            f32x4 c0; c0[0] = b1v[ni]; c0[1] = b1v[ni]; c0[2] = b1v[ni]; c0[3] = b1v[ni];
            f32x4 z = MFMA32(ak0.s, bw0, c0);
            z = MFMA32(ak1.s, bw1, z);
            z1a[ni] = z;
            f32x4 zq = MFMA32(aq0.s, bw0, c0);
            zq = MFMA32(aq1.s, bw1, zq);
            zqa[ni] = zq;
        }
        f32x4 at_; at_[0] = 0.f; at_[1] = 0.f; at_[2] = 0.f; at_[3] = 0.f;
        at_ = MFMA32(aq0.s, ak0.s, at_);
        at_ = MFMA32(aq1.s, ak1.s, at_);

#pragma unroll
        for (int ni = 0; ni < 4; ++ni)
#pragma unroll
            for (int r = 0; r < 4; ++r)
                sZ1[(4 * gq + r) * 68 + 16 * ni + lc] = z1a[ni][r];
#pragma unroll
        for (int r = 0; r < 4; ++r) sAttn[(4 * gq + r) * 20 + lc] = at_[r];

        // ======== LN-bwd in row layout (single-pass 6-sum) ========
        f32x4 t2a[4];
        float S1 = 0.f, S2 = 0.f, S3 = 0.f, S4 = 0.f, S5 = 0.f, S6 = 0.f;
        f32x4 zr[4];
#pragma unroll
        for (int c4 = 0; c4 < 4; ++c4)
            zr[c4] = *(const f32x4*)&sZ1[s * 68 + 16 * q + 4 * c4];
#pragma unroll
        for (int c4 = 0; c4 < 4; ++c4)
#pragma unroll
            for (int c = 0; c < 4; ++c) {
                const float ga = gam4[c4][c];
                const float t2 = fmaf(-ga, fv[c4][c] - rk[c4][c], ga * bet4[c4][c]);
                t2a[c4][c] = t2;
                const float z = zr[c4][c];
                const float c1z = ga * ga * z;
                S1 += z;  S2 = fmaf(z, z, S2);
                S3 += c1z; S4 = fmaf(c1z, z, S4);
                S5 += t2;  S6 = fmaf(t2, z, S6);
            }
        // reissue xv row prefetch for m+1
        if (m + 1 < NMB) {
            const size_t o = (size_t)(m + 1) * 1024;
#pragma unroll
            for (int c4 = 0; c4 < 4; ++c4)
                fv[c4] = *(const f32x4*)&xvg[o + s * 64 + 16 * q + 4 * c4];
        }
        S1 += __shfl_xor(S1, 1); S1 += __shfl_xor(S1, 2);
        S2 += __shfl_xor(S2, 1); S2 += __shfl_xor(S2, 2);
        S3 += __shfl_xor(S3, 1); S3 += __shfl_xor(S3, 2);
        S4 += __shfl_xor(S4, 1); S4 += __shfl_xor(S4, 2);
        S5 += __shfl_xor(S5, 1); S5 += __shfl_xor(S5, 2);
        S6 += __shfl_xor(S6, 1); S6 += __shfl_xor(S6, 2);

        const float mu   = S1 * (1.f / 64.f);
        const float rstd = rsqrtf(S2 * (1.f / 64.f) - mu * mu + 1e-6f);
        const float r1 = rstd * (S3 - mu * sc1) + S5;
        const float r2 = rstd * rstd * (S4 - 2.f * mu * S3 + mu * mu * sc1)
                       + rstd * (S6 - mu * S5);
        const float cf = rstd * (1.f / 64.f);

        float gv[16];
#pragma unroll
        for (int c4 = 0; c4 < 4; ++c4)
#pragma unroll
            for (int c = 0; c < 4; ++c) {
                const float z  = zr[c4][c];
                const float xh = (z - mu) * rstd;
                const float gx = fmaf(gam4[c4][c] * gam4[c4][c], xh, t2a[c4][c]);
                gv[4 * c4 + c] = (fmaf(64.f, gx, -r1) - xh * r2) * cf;
            }

        // ======== stage g and -le*xk into tr-read tiles ========
        const int tbS = (s >> 2) * 256 + q * 64 + (s & 3) * 16;
        {
            U4S8 g0, g1;
            g0.u[0] = pkbf(gv[0], gv[1]);  g0.u[1] = pkbf(gv[2], gv[3]);
            g0.u[2] = pkbf(gv[4], gv[5]);  g0.u[3] = pkbf(gv[6], gv[7]);
            g1.u[0] = pkbf(gv[8], gv[9]);  g1.u[1] = pkbf(gv[10], gv[11]);
            g1.u[2] = pkbf(gv[12], gv[13]); g1.u[3] = pkbf(gv[14], gv[15]);
            *(short8*)&sGt[tbS] = g0.s;
            *(short8*)&sGt[tbS + 8] = g1.s;
            U4S8 k0, k1;
            k0.u[0] = pkbf(-lesv * rk[0][0], -lesv * rk[0][1]);
            k0.u[1] = pkbf(-lesv * rk[0][2], -lesv * rk[0][3]);
            k0.u[2] = pkbf(-lesv * rk[1][0], -lesv * rk[1][1]);
            k0.u[3] = pkbf(-lesv * rk[1][2], -lesv * rk[1][3]);
            k1.u[0] = pkbf(-lesv * rk[2][0], -lesv * rk[2][1]);
            k1.u[1] = pkbf(-lesv * rk[2][2], -lesv * rk[2][3]);
            k1.u[2] = pkbf(-lesv * rk[3][0], -lesv * rk[3][1]);
            k1.u[3] = pkbf(-lesv * rk[3][2], -lesv * rk[3][3]);
            *(short8*)&sXKe[tbS] = k0.s;
            *(short8*)&sXKe[tbS + 8] = k1.s;
        }
        if (m + 1 < NMB) lesv = etg[(size_t)(m + 1) * 256 + 240 + s];

        // ======== build -E and -le A-frags in registers ========
        f32x4 at0 = *(const f32x4*)&sAttn[lc * 20 + ecol];
        f32x4 at1 = *(const f32x4*)&sAttn[lc * 20 + ecol + 4];
        U4S8 aE, aL;
        {
            float ev[8] = {ea0[0], ea0[1], ea0[2], ea0[3], ea1[0], ea1[1], ea1[2], ea1[3]};
            float av[8] = {at0[0], at0[1], at0[2], at0[3], at1[0], at1[1], at1[2], at1[3]};
            float lv[8] = {le0[0], le0[1], le0[2], le0[3], le1[0], le1[1], le1[2], le1[3]};
#pragma unroll
            for (int p = 0; p < 4; ++p) {
                const int j0 = 8 * gq + 2 * p, j1 = j0 + 1;
                const float x0 = (j0 <= lc) ? -ev[2 * p] * (1.f + av[2 * p]) : 0.f;
                const float x1 = (j1 <= lc) ? -ev[2 * p + 1] * (1.f + av[2 * p + 1]) : 0.f;
                aE.u[p] = pkbf(x0, x1);
                const float y0 = (gq < 2) ? -lv[2 * p] : 0.f;
                const float y1 = (gq < 2) ? -lv[2 * p + 1] : 0.f;
                aL.u[p] = pkbf(y0, y1);
            }
        }
        if (m + 1 < NMB) {
            const size_t o = (size_t)(m + 1) * 256;
            ea0 = *(const f32x4*)&etg[o + lc * 16 + ecol];
            ea1 = *(const f32x4*)&etg[o + lc * 16 + ecol + 4];
            le0 = *(const f32x4*)&etg[o + 240 + ecol];
            le1 = *(const f32x4*)&etg[o + 240 + ecol + 4];
        }

        // ======== tr-reads of g^T and (-le*xk)^T ========
        const unsigned gb_ = (unsigned)(size_t)&sGt[0] + 1024u * gq + 8u * lc;
        const unsigned kb_ = (unsigned)(size_t)&sXKe[0] + 1024u * gq + 8u * lc;
        short4_t bgl0, bgl1, bgl2, bgl3, bgh0, bgh1, bgh2, bgh3;
        short4_t akl0, akl1, akl2, akl3, akh0, akh1, akh2, akh3;
        TR_READ(bgl0, gb_, "0");   TR_READ(bgh0, gb_, "512");
        TR_READ(bgl1, gb_, "128"); TR_READ(bgh1, gb_, "640");
        TR_READ(bgl2, gb_, "256"); TR_READ(bgh2, gb_, "768");
        TR_READ(bgl3, gb_, "384"); TR_READ(bgh3, gb_, "896");
        TR_READ(akl0, kb_, "0");   TR_READ(akh0, kb_, "512");
        TR_READ(akl1, kb_, "128"); TR_READ(akh1, kb_, "640");
        TR_READ(akl2, kb_, "256"); TR_READ(akh2, kb_, "768");
        TR_READ(akl3, kb_, "384"); TR_READ(akh3, kb_, "896");
        asm volatile("s_waitcnt lgkmcnt(0)" ::: "memory");
        __builtin_amdgcn_sched_barrier(0);

        const short8 bg[4] = {cmb(bgl0, bgh0), cmb(bgl1, bgh1), cmb(bgl2, bgh2), cmb(bgl3, bgh3)};
        const short8 akt[4] = {cmb(akl0, akh0), cmb(akl1, akh1), cmb(akl2, akh2), cmb(akl3, akh3)};

        // ======== MFMA2: W update, Z1_bar, b1 update ========
#pragma unroll
        for (int mi = 0; mi < 4; ++mi)
#pragma unroll
            for (int ni = 0; ni < 4; ++ni)
                Wacc[mi][ni] = MFMA32(akt[mi], bg[ni], Wacc[mi][ni]);

        f32x4 zb[4];
#pragma unroll
        for (int ni = 0; ni < 4; ++ni) {
            zb[ni] = MFMA32(aE.s, bg[ni], zqa[ni]);
            f32x4 d0; d0[0] = 0.f; d0[1] = 0.f; d0[2] = 0.f; d0[3] = 0.f;
            d0 = MFMA32(aL.s, bg[ni], d0);
            b1v[ni] += d0[0];
        }

        // mirror updated W to sWt (for next step's MFMA1)
#pragma unroll
        for (int mi = 0; mi < 4; ++mi)
#pragma unroll
            for (int ni = 0; ni < 4; ++ni) {
                U2S4 wp;
                wp.u[0] = pkbf(Wacc[mi][ni][0], Wacc[mi][ni][1]);
                wp.u[1] = pkbf(Wacc[mi][ni][2], Wacc[mi][ni][3]);
                *(short4_t*)&sWt[(16 * ni + lc) * 72 + 16 * mi + 4 * gq] = wp.s;
            }

        // ======== LN-fwd + output (row layout) ========
#pragma unroll
        for (int ni = 0; ni < 4; ++ni)
#pragma unroll
            for (int r = 0; r < 4; ++r)
                sZb[(4 * gq + r) * 68 + 16 * ni + lc] = zb[ni][r];

        f32x4 zbr[4];
#pragma unroll
        for (int c4 = 0; c4 < 4; ++c4)
            zbr[c4] = *(const f32x4*)&sZb[s * 68 + 16 * q + 4 * c4];
        float T1 = 0.f, T2 = 0.f;
#pragma unroll
        for (int c4 = 0; c4 < 4; ++c4)
#pragma unroll
            for (int c = 0; c < 4; ++c) {
                const float z = zbr[c4][c];
                T1 += z; T2 = fmaf(z, z, T2);
            }
        T1 += __shfl_xor(T1, 1); T1 += __shfl_xor(T1, 2);
        T2 += __shfl_xor(T2, 1); T2 += __shfl_xor(T2, 2);
        const float mu2   = T1 * (1.f / 64.f);
        const float rstd2 = rsqrtf(T2 * (1.f / 64.f) - mu2 * mu2 + 1e-6f);

        const size_t oi = ((size_t)b * 4096 + (size_t)m * 16 + s) * 512 + h * 64 + 16 * q;
#pragma unroll
        for (int c4 = 0; c4 < 4; ++c4) {
            f32x4 o;
#pragma unroll
            for (int c = 0; c < 4; ++c)
                o[c] = rq[c4][c] + fmaf(gam4[c4][c], (zbr[c4][c] - mu2) * rstd2, bet4[c4][c]);
            *(f32x4*)&gOUT[oi + 4 * c4] = o;
        }
    }
}

extern "C" void kernel_launch(void* const* d_in, const int* in_sizes, int n_in,
                              void* d_out, int out_size, void* d_ws, size_t ws_size,
                              hipStream_t stream) {
    const float* XQ  = (const float*)d_in[0];
    const float* XK  = (const float*)d_in[1];
    const float* XV  = (const float*)d_in[2];
    const float* ETA = (const float*)d_in[3];
    const float* W1  = (const float*)d_in[4];
    const float* B1  = (const float*)d_in[5];
    const float* LNW = (const float*)d_in[6];
    const float* LNB = (const float*)d_in[7];
    float* OUT = (float*)d_out;

    const int n_chains = in_sizes[0] / (NMB * MBS * HD);   // B*nh = 64
    ttt_scan<<<n_chains, 64, 0, stream>>>(XQ, XK, XV, ETA, W1, B1, LNW, LNB, OUT);
}

// Round 6
// 530.701 us; speedup vs baseline: 1.5652x; 1.5652x over previous
//
#include <hip/hip_runtime.h>
#include <hip/hip_bf16.h>

typedef __attribute__((ext_vector_type(8))) short short8;
typedef __attribute__((ext_vector_type(4))) short short4_t;
typedef __attribute__((ext_vector_type(4))) float f32x4;

constexpr int MBS = 16, HD = 64, NMB = 256;

#define MFMA32(a, b, c) __builtin_amdgcn_mfma_f32_16x16x32_bf16(a, b, c, 0, 0, 0)
#define TR_READ(dst, addr, IMM) \
    asm volatile("ds_read_b64_tr_b16 %0, %1 offset:" IMM : "=&v"(dst) : "v"(addr) : "memory")

union U4S8 { unsigned u[4]; short8 s; };
union U2S4 { unsigned u[2]; short4_t s; };

__device__ inline unsigned pkbf(float a, float b) {
    union { __hip_bfloat162 h; unsigned u; } c;
    c.h = __float22bfloat162_rn(make_float2(a, b));
    return c.u;
}
__device__ inline short8 cmb(short4_t a, short4_t b) {
    short8 r;
    r[0]=a[0]; r[1]=a[1]; r[2]=a[2]; r[3]=a[3];
    r[4]=b[0]; r[5]=b[1]; r[6]=b[2]; r[7]=b[3];
    return r;
}
// raw barrier: LDS writes made visible (lgkmcnt) but global loads stay in flight
__device__ inline void bar() {
    __builtin_amdgcn_sched_barrier(0);
    asm volatile("s_waitcnt lgkmcnt(0)" ::: "memory");
    __builtin_amdgcn_s_barrier();
    __builtin_amdgcn_sched_barrier(0);
}

__global__ __launch_bounds__(256) void ttt_scan(
    const float* __restrict__ gXQ, const float* __restrict__ gXK,
    const float* __restrict__ gXV, const float* __restrict__ gETA,
    const float* __restrict__ gW1, const float* __restrict__ gB1,
    const float* __restrict__ gLNW, const float* __restrict__ gLNB,
    float* __restrict__ gOUT)
{
    __shared__ __align__(16) short sWt[64 * 72];   // W^T bf16 [n][k], stride 72
    __shared__ __align__(16) short bxk[16 * 72];   // xk bf16 [s][d]
    __shared__ __align__(16) short bxq[16 * 72];   // xq bf16 [s][d]
    __shared__ __align__(16) short sGt[2048];      // g tiled; jblk 4..7 permanently 0
    __shared__ __align__(16) short sXKe[2048];     // -le*xk tiled; hi jblks 0
    __shared__ __align__(16) short sE[16 * 40];    // -E [r][j], j zero-padded to 32
    __shared__ __align__(16) float sZ1[16 * 68];
    __shared__ __align__(16) float sZb[16 * 68];
    __shared__ __align__(16) float sAttn[16 * 20];
    __shared__ float sEta[256];
    __shared__ float sB1[64];
    __shared__ float sB1p[4 * 64];

    const int t  = threadIdx.x;
    const int s  = t >> 4;        // thread-layout row
    const int dt = t & 15;        // thread-layout col group (4 cols)
    const int lane = t & 63;
    const int w  = t >> 6;        // wave id
    const int gq = lane >> 4;     // 16-lane group
    const int lc = lane & 15;
    const int bh = blockIdx.x, b = bh >> 3, h = bh & 7;

    const float* xqg = gXQ + (size_t)bh * (NMB * MBS * HD);
    const float* xkg = gXK + (size_t)bh * (NMB * MBS * HD);
    const float* xvg = gXV + (size_t)bh * (NMB * MBS * HD);
    const float* etg = gETA + (size_t)bh * (NMB * MBS * MBS);

    // zero tiled/padded bf16 buffers (hi-jblk stays 0 forever)
    for (int i = t; i < 2048; i += 256) { sGt[i] = 0; sXKe[i] = 0; }
    for (int i = t; i < 16 * 40; i += 256) sE[i] = 0;

    // W state: wave w owns rows [16w,16w+16) as 4 C-fragments + bf16 mirror
    f32x4 Wacc[4];
#pragma unroll
    for (int ct = 0; ct < 4; ++ct) {
#pragma unroll
        for (int r = 0; r < 4; ++r)
            Wacc[ct][r] = gW1[h * 4096 + (16 * w + 4 * gq + r) * 64 + 16 * ct + lc];
        U2S4 wp;
        wp.u[0] = pkbf(Wacc[ct][0], Wacc[ct][1]);
        wp.u[1] = pkbf(Wacc[ct][2], Wacc[ct][3]);
        *(short4_t*)&sWt[(16 * ct + lc) * 72 + 16 * w + 4 * gq] = wp.s;
    }
    if (t < 64) sB1[t] = gB1[h * 64 + t];

    const float4 gam = *(const float4*)&gLNW[h * 64 + dt * 4];
    const float4 bet = *(const float4*)&gLNB[h * 64 + dt * 4];
    const float ga[4] = {gam.x, gam.y, gam.z, gam.w};
    const float ba[4] = {bet.x, bet.y, bet.z, bet.w};
    float c1a[4], gba[4];
    float sc1 = 0.f;
#pragma unroll
    for (int c = 0; c < 4; ++c) {
        c1a[c] = ga[c] * ga[c];
        gba[c] = ga[c] * ba[c];
        sc1 += c1a[c];
    }
    sc1 += __shfl_xor(sc1, 1); sc1 += __shfl_xor(sc1, 2);
    sc1 += __shfl_xor(sc1, 4); sc1 += __shfl_xor(sc1, 8);

    // prefetch minibatch 0
    float4 pq = *(const float4*)&xqg[t * 4];
    float4 pk = *(const float4*)&xkg[t * 4];
    float4 pv = *(const float4*)&xvg[t * 4];
    float4 pe = make_float4(0.f, 0.f, 0.f, 0.f);
    if (t < 64) pe = *(const float4*)&etg[t * 4];

    __syncthreads();   // init barrier (full drain fine here, once)

#pragma unroll 1
    for (int m = 0; m < NMB; ++m) {
        // ======== STAGE (no pre-barrier: writes don't clash with prev THREAD2 reads) ====
        short4_t kk; { U2S4 u_; u_.u[0]=pkbf(pk.x,pk.y); u_.u[1]=pkbf(pk.z,pk.w); kk=u_.s; }
        short4_t qq; { U2S4 u_; u_.u[0]=pkbf(pq.x,pq.y); u_.u[1]=pkbf(pq.z,pq.w); qq=u_.s; }
        *(short4_t*)&bxk[s * 72 + dt * 4] = kk;
        *(short4_t*)&bxq[s * 72 + dt * 4] = qq;
        if (t < 64) *(float4*)&sEta[t * 4] = pe;
        float t2c[4];
        {
            const float pva[4] = {pv.x, pv.y, pv.z, pv.w};
            const float pka_[4] = {pk.x, pk.y, pk.z, pk.w};
#pragma unroll
            for (int c = 0; c < 4; ++c)
                t2c[c] = fmaf(-ga[c], pva[c] - pka_[c], gba[c]);
        }
        const float4 pqc = pq, pkc = pk;
        bar();   // (B)

        // global prefetch for m+1 — stays in flight across all raw barriers
        if (m + 1 < NMB) {
            const size_t o = (size_t)(m + 1) * (MBS * HD) + t * 4;
            pq = *(const float4*)&xqg[o];
            pk = *(const float4*)&xkg[o];
            pv = *(const float4*)&xvg[o];
            if (t < 64) pe = *(const float4*)&etg[(size_t)(m + 1) * (MBS * MBS) + t * 4];
        }

        // ======== MFMA1: Z1 = xk@W + b1 ; Zq = xq@W + b1 ; Attn ========
        const float b1v = sB1[16 * w + lc];
        f32x4 z1a; z1a[0]=b1v; z1a[1]=b1v; z1a[2]=b1v; z1a[3]=b1v;
        f32x4 zqa = z1a;
        const short8 ak0 = *(const short8*)&bxk[lc * 72 + gq * 8];
        const short8 ak1 = *(const short8*)&bxk[lc * 72 + gq * 8 + 32];
        const short8 aq0 = *(const short8*)&bxq[lc * 72 + gq * 8];
        const short8 aq1 = *(const short8*)&bxq[lc * 72 + gq * 8 + 32];
        const short8 bw0 = *(const short8*)&sWt[(16 * w + lc) * 72 + gq * 8];
        const short8 bw1 = *(const short8*)&sWt[(16 * w + lc) * 72 + gq * 8 + 32];
        z1a = MFMA32(ak0, bw0, z1a); z1a = MFMA32(ak1, bw1, z1a);
        zqa = MFMA32(aq0, bw0, zqa); zqa = MFMA32(aq1, bw1, zqa);
#pragma unroll
        for (int r = 0; r < 4; ++r) sZ1[(4 * gq + r) * 68 + 16 * w + lc] = z1a[r];
        if (w == 3) {
            f32x4 zz; zz[0]=0.f; zz[1]=0.f; zz[2]=0.f; zz[3]=0.f;
            zz = MFMA32(aq0, ak0, zz); zz = MFMA32(aq1, ak1, zz);
#pragma unroll
            for (int r = 0; r < 4; ++r) sAttn[(4 * gq + r) * 20 + lc] = zz[r];
        }
        bar();   // (C)

        // ======== THREAD1: LN-bwd (single-pass 6-sum) -> g ; stage g^T, xke^T, E ====
        f32x4 z = *(f32x4*)&sZ1[s * 68 + dt * 4];
        float S1=0.f,S2=0.f,S3=0.f,S4=0.f,S5=0.f,S6=0.f;
#pragma unroll
        for (int c = 0; c < 4; ++c) {
            const float zc = z[c], c1z = c1a[c] * zc, t2 = t2c[c];
            S1 += zc;  S2 = fmaf(zc, zc, S2);
            S3 += c1z; S4 = fmaf(c1z, zc, S4);
            S5 += t2;  S6 = fmaf(t2, zc, S6);
        }
#pragma unroll
        for (int msk = 1; msk < 16; msk <<= 1) {
            S1 += __shfl_xor(S1, msk); S2 += __shfl_xor(S2, msk);
            S3 += __shfl_xor(S3, msk); S4 += __shfl_xor(S4, msk);
            S5 += __shfl_xor(S5, msk); S6 += __shfl_xor(S6, msk);
        }
        const float mu   = S1 * (1.f / 64.f);
        const float rstd = rsqrtf(S2 * (1.f / 64.f) - mu * mu + 1e-6f);
        const float r1 = rstd * (S3 - mu * sc1) + S5;
        const float r2 = rstd * rstd * (S4 - 2.f * mu * S3 + mu * mu * sc1)
                       + rstd * (S6 - mu * S5);
        const float cf = rstd * (1.f / 64.f);
        float g[4];
#pragma unroll
        for (int c = 0; c < 4; ++c) {
            const float xh = (z[c] - mu) * rstd;
            const float gx = fmaf(c1a[c], xh, t2c[c]);
            g[c] = (fmaf(64.f, gx, -r1) - xh * r2) * cf;
        }

        const float le = sEta[240 + s];
        const int tb = (s >> 2) * 256 + (dt >> 2) * 64 + (s & 3) * 16 + (dt & 3) * 4;
        { U2S4 gp; gp.u[0]=pkbf(g[0],g[1]); gp.u[1]=pkbf(g[2],g[3]);
          *(short4_t*)&sGt[tb] = gp.s; }
        { U2S4 kp; kp.u[0]=pkbf(-le*pkc.x,-le*pkc.y); kp.u[1]=pkbf(-le*pkc.z,-le*pkc.w);
          *(short4_t*)&sXKe[tb] = kp.s; }

        // b1 partial: sum over wave's 4 s-rows of le*g
        f32x4 bp;
#pragma unroll
        for (int c = 0; c < 4; ++c) {
            float v = le * g[c];
            v += __shfl_xor(v, 16);
            v += __shfl_xor(v, 32);
            bp[c] = v;
        }
        if (gq == 0) *(f32x4*)&sB1p[w * 64 + dt * 4] = bp;

        // E = tril*eta*(1+Attn); store -E (cols 0..15; 16..31 stay 0)
        if (dt < 4) {
            f32x4 at = *(f32x4*)&sAttn[s * 20 + dt * 4];
            f32x4 ev = *(f32x4*)&sEta[s * 16 + dt * 4];
            U2S4 ep;
            float x[4];
#pragma unroll
            for (int c = 0; c < 4; ++c) {
                const int cc = 4 * dt + c;
                x[c] = (cc <= s) ? -ev[c] * (1.f + at[c]) : 0.f;
            }
            ep.u[0] = pkbf(x[0], x[1]); ep.u[1] = pkbf(x[2], x[3]);
            *(short4_t*)&sE[s * 40 + 4 * dt] = ep.s;
        }
        bar();   // (D)

        // ======== MFMA2: Z1_bar = Zq - E@g ; W -= (le*xk)^T @ g ========
        const unsigned gbase = (unsigned)(size_t)&sGt[0] + 1024u * gq + 8u * lc;
        const unsigned ebase = gbase + 128u * (unsigned)w;
        const unsigned kbase = (unsigned)(size_t)&sXKe[0] + 1024u * gq + 8u * lc
                             + 128u * (unsigned)w;
        short4_t elo, ehi, al, ah;
        short4_t bl0, bh0, bl1, bh1, bl2, bh2, bl3, bh3;
        TR_READ(elo, ebase, "0");   TR_READ(ehi, ebase, "512");
        TR_READ(al,  kbase, "0");   TR_READ(ah,  kbase, "512");
        TR_READ(bl0, gbase, "0");   TR_READ(bh0, gbase, "512");
        TR_READ(bl1, gbase, "128"); TR_READ(bh1, gbase, "640");
        TR_READ(bl2, gbase, "256"); TR_READ(bh2, gbase, "768");
        TR_READ(bl3, gbase, "384"); TR_READ(bh3, gbase, "896");
        const short8 aE = *(const short8*)&sE[lc * 40 + gq * 8];
        asm volatile("s_waitcnt lgkmcnt(0)" ::: "memory");
        __builtin_amdgcn_sched_barrier(0);

        f32x4 zb = MFMA32(aE, cmb(elo, ehi), zqa);
#pragma unroll
        for (int r = 0; r < 4; ++r) sZb[(4 * gq + r) * 68 + 16 * w + lc] = zb[r];

        const short8 aK = cmb(al, ah);
        Wacc[0] = MFMA32(aK, cmb(bl0, bh0), Wacc[0]);
        Wacc[1] = MFMA32(aK, cmb(bl1, bh1), Wacc[1]);
        Wacc[2] = MFMA32(aK, cmb(bl2, bh2), Wacc[2]);
        Wacc[3] = MFMA32(aK, cmb(bl3, bh3), Wacc[3]);
#pragma unroll
        for (int ct = 0; ct < 4; ++ct) {
            U2S4 wp;
            wp.u[0] = pkbf(Wacc[ct][0], Wacc[ct][1]);
            wp.u[1] = pkbf(Wacc[ct][2], Wacc[ct][3]);
            *(short4_t*)&sWt[(16 * ct + lc) * 72 + 16 * w + 4 * gq] = wp.s;
        }
        bar();   // (E)

        // ======== THREAD2: LN-fwd + output ; b1 update ========
        f32x4 zbr = *(f32x4*)&sZb[s * 68 + dt * 4];
        float T1 = 0.f, T2 = 0.f;
#pragma unroll
        for (int c = 0; c < 4; ++c) { T1 += zbr[c]; T2 = fmaf(zbr[c], zbr[c], T2); }
#pragma unroll
        for (int msk = 1; msk < 16; msk <<= 1) {
            T1 += __shfl_xor(T1, msk); T2 += __shfl_xor(T2, msk);
        }
        const float mu2   = T1 * (1.f / 64.f);
        const float rstd2 = rsqrtf(T2 * (1.f / 64.f) - mu2 * mu2 + 1e-6f);
        const float pqa[4] = {pqc.x, pqc.y, pqc.z, pqc.w};
        float o[4];
#pragma unroll
        for (int c = 0; c < 4; ++c)
            o[c] = pqa[c] + fmaf(ga[c], (zbr[c] - mu2) * rstd2, ba[c]);
        const size_t oi = ((size_t)b * 4096 + (size_t)m * 16 + s) * 512 + h * 64 + dt * 4;
        *(float4*)&gOUT[oi] = make_float4(o[0], o[1], o[2], o[3]);

        if (t < 64) {
            const float bsum = sB1p[t] + sB1p[64 + t] + sB1p[128 + t] + sB1p[192 + t];
            sB1[t] -= bsum;
        }
    }
}

extern "C" void kernel_launch(void* const* d_in, const int* in_sizes, int n_in,
                              void* d_out, int out_size, void* d_ws, size_t ws_size,
                              hipStream_t stream) {
    const float* XQ  = (const float*)d_in[0];
    const float* XK  = (const float*)d_in[1];
    const float* XV  = (const float*)d_in[2];
    const float* ETA = (const float*)d_in[3];
    const float* W1  = (const float*)d_in[4];
    const float* B1  = (const float*)d_in[5];
    const float* LNW = (const float*)d_in[6];
    const float* LNB = (const float*)d_in[7];
    float* OUT = (float*)d_out;

    const int n_chains = in_sizes[0] / (NMB * MBS * HD);   // B*nh = 64
    ttt_scan<<<n_chains, 256, 0, stream>>>(XQ, XK, XV, ETA, W1, B1, LNW, LNB, OUT);
}

// Round 7
// 455.353 us; speedup vs baseline: 1.8242x; 1.1655x over previous
//
#include <hip/hip_runtime.h>
#include <hip/hip_bf16.h>

typedef __attribute__((ext_vector_type(8))) short short8;
typedef __attribute__((ext_vector_type(4))) short short4_t;
typedef __attribute__((ext_vector_type(4))) float f32x4;

constexpr int MBS = 16, HD = 64, NMB = 256;

#define MFMA32(a, b, c) __builtin_amdgcn_mfma_f32_16x16x32_bf16(a, b, c, 0, 0, 0)
#define TR_READ(dst, addr, IMM) \
    asm volatile("ds_read_b64_tr_b16 %0, %1 offset:" IMM : "=&v"(dst) : "v"(addr) : "memory")

union U4S8 { unsigned u[4]; short8 s; };
union U2S4 { unsigned u[2]; short4_t s; };
union FI { float f; int i; };

__device__ inline unsigned pkbf(float a, float b) {
    union { __hip_bfloat162 h; unsigned u; } c;
    c.h = __float22bfloat162_rn(make_float2(a, b));
    return c.u;
}
__device__ inline short8 cmb(short4_t a, short4_t b) {
    short8 r;
    r[0]=a[0]; r[1]=a[1]; r[2]=a[2]; r[3]=a[3];
    r[4]=b[0]; r[5]=b[1]; r[6]=b[2]; r[7]=b[3];
    return r;
}
// all-VALU 16-lane sum reduce: quad_perm xor1, xor2, then row_ror 4, 8
__device__ inline float dpp16(float x) {
    FI v; v.f = x; FI t;
    t.i = __builtin_amdgcn_update_dpp(0, v.i, 0xB1, 0xf, 0xf, true);  v.f += t.f;
    t.i = __builtin_amdgcn_update_dpp(0, v.i, 0x4E, 0xf, 0xf, true);  v.f += t.f;
    t.i = __builtin_amdgcn_update_dpp(0, v.i, 0x124, 0xf, 0xf, true); v.f += t.f;
    t.i = __builtin_amdgcn_update_dpp(0, v.i, 0x128, 0xf, 0xf, true); v.f += t.f;
    return v.f;
}
// raw barrier: LDS writes visible, global loads stay in flight
__device__ inline void bar() {
    __builtin_amdgcn_sched_barrier(0);
    asm volatile("s_waitcnt lgkmcnt(0)" ::: "memory");
    __builtin_amdgcn_s_barrier();
    __builtin_amdgcn_sched_barrier(0);
}

__global__ __launch_bounds__(256) void ttt_scan(
    const float* __restrict__ gXQ, const float* __restrict__ gXK,
    const float* __restrict__ gXV, const float* __restrict__ gETA,
    const float* __restrict__ gW1, const float* __restrict__ gB1,
    const float* __restrict__ gLNW, const float* __restrict__ gLNB,
    float* __restrict__ gOUT)
{
    __shared__ __align__(16) short sWt[64 * 72];   // W^T bf16 [n][k], stride 72
    __shared__ __align__(16) short bxk[16 * 72];
    __shared__ __align__(16) short bxq[16 * 72];
    __shared__ __align__(16) short sGt[2048];      // g tiled; jblk 4..7 permanently 0
    __shared__ __align__(16) short sXKe[2048];     // -le*xk tiled; hi jblks 0
    __shared__ __align__(16) short sE[16 * 40];    // -E [r][j], j zero-padded to 32
    __shared__ __align__(16) float sZ1[16 * 68];
    __shared__ __align__(16) float sZb[16 * 68];
    __shared__ __align__(16) float sAttn[16 * 20];
    __shared__ float sEta[256];
    __shared__ float sB1[64];
    __shared__ float sB1p[4 * 64];

    const int t  = threadIdx.x;
    const int s  = t >> 4;
    const int dt = t & 15;
    const int lane = t & 63;
    const int w  = t >> 6;
    const int gq = lane >> 4;
    const int lc = lane & 15;
    const int bh = blockIdx.x, b = bh >> 3, h = bh & 7;

    const float* xqg = gXQ + (size_t)bh * (NMB * MBS * HD);
    const float* xkg = gXK + (size_t)bh * (NMB * MBS * HD);
    const float* xvg = gXV + (size_t)bh * (NMB * MBS * HD);
    const float* etg = gETA + (size_t)bh * (NMB * MBS * MBS);

    for (int i = t; i < 2048; i += 256) { sGt[i] = 0; sXKe[i] = 0; }
    for (int i = t; i < 16 * 40; i += 256) sE[i] = 0;

    f32x4 Wacc[4];
#pragma unroll
    for (int ct = 0; ct < 4; ++ct) {
#pragma unroll
        for (int r = 0; r < 4; ++r)
            Wacc[ct][r] = gW1[h * 4096 + (16 * w + 4 * gq + r) * 64 + 16 * ct + lc];
        U2S4 wp;
        wp.u[0] = pkbf(Wacc[ct][0], Wacc[ct][1]);
        wp.u[1] = pkbf(Wacc[ct][2], Wacc[ct][3]);
        *(short4_t*)&sWt[(16 * ct + lc) * 72 + 16 * w + 4 * gq] = wp.s;
    }
    if (t < 64) sB1[t] = gB1[h * 64 + t];

    const float4 gam = *(const float4*)&gLNW[h * 64 + dt * 4];
    const float4 bet = *(const float4*)&gLNB[h * 64 + dt * 4];
    const float ga[4] = {gam.x, gam.y, gam.z, gam.w};
    const float ba[4] = {bet.x, bet.y, bet.z, bet.w};
    float c1a[4], gba[4];
    float sc1 = 0.f;
#pragma unroll
    for (int c = 0; c < 4; ++c) {
        c1a[c] = ga[c] * ga[c];
        gba[c] = ga[c] * ba[c];
        sc1 += c1a[c];
    }
    sc1 = dpp16(sc1);

    float4 pq = *(const float4*)&xqg[t * 4];
    float4 pk = *(const float4*)&xkg[t * 4];
    float4 pv = *(const float4*)&xvg[t * 4];
    float4 pe = make_float4(0.f, 0.f, 0.f, 0.f);
    if (t < 64) pe = *(const float4*)&etg[t * 4];
    float4 pq_prev;

    __syncthreads();

#pragma unroll 1
    for (int m = 0; m < NMB; ++m) {
        // ======== STAGE ========
        short4_t kk; { U2S4 u_; u_.u[0]=pkbf(pk.x,pk.y); u_.u[1]=pkbf(pk.z,pk.w); kk=u_.s; }
        short4_t qq; { U2S4 u_; u_.u[0]=pkbf(pq.x,pq.y); u_.u[1]=pkbf(pq.z,pq.w); qq=u_.s; }
        *(short4_t*)&bxk[s * 72 + dt * 4] = kk;
        *(short4_t*)&bxq[s * 72 + dt * 4] = qq;
        if (t < 64) *(float4*)&sEta[t * 4] = pe;
        float t2c[4];
        {
            const float pva[4] = {pv.x, pv.y, pv.z, pv.w};
            const float pka_[4] = {pk.x, pk.y, pk.z, pk.w};
#pragma unroll
            for (int c = 0; c < 4; ++c)
                t2c[c] = fmaf(-ga[c], pva[c] - pka_[c], gba[c]);
        }
        const float4 pqc = pq, pkc = pk;
        bar();   // (B)

        // prefetch m+1 — stays in flight across raw barriers
        if (m + 1 < NMB) {
            const size_t o = (size_t)(m + 1) * (MBS * HD) + t * 4;
            pq = *(const float4*)&xqg[o];
            pk = *(const float4*)&xkg[o];
            pv = *(const float4*)&xvg[o];
            if (t < 64) pe = *(const float4*)&etg[(size_t)(m + 1) * (MBS * MBS) + t * 4];
        }

        // ======== MFMA1 (+ deferred THREAD2 of step m-1 overlapped) ========
        const float b1v = sB1[16 * w + lc];
        f32x4 z1a; z1a[0]=b1v; z1a[1]=b1v; z1a[2]=b1v; z1a[3]=b1v;
        f32x4 zqa = z1a;
        const short8 ak0 = *(const short8*)&bxk[lc * 72 + gq * 8];
        const short8 ak1 = *(const short8*)&bxk[lc * 72 + gq * 8 + 32];
        const short8 aq0 = *(const short8*)&bxq[lc * 72 + gq * 8];
        const short8 aq1 = *(const short8*)&bxq[lc * 72 + gq * 8 + 32];
        const short8 bw0 = *(const short8*)&sWt[(16 * w + lc) * 72 + gq * 8];
        const short8 bw1 = *(const short8*)&sWt[(16 * w + lc) * 72 + gq * 8 + 32];
        z1a = MFMA32(ak0, bw0, z1a); z1a = MFMA32(ak1, bw1, z1a);
        zqa = MFMA32(aq0, bw0, zqa); zqa = MFMA32(aq1, bw1, zqa);
#pragma unroll
        for (int r = 0; r < 4; ++r) sZ1[(4 * gq + r) * 68 + 16 * w + lc] = z1a[r];
        if (w == 3) {
            f32x4 zz; zz[0]=0.f; zz[1]=0.f; zz[2]=0.f; zz[3]=0.f;
            zz = MFMA32(aq0, ak0, zz); zz = MFMA32(aq1, ak1, zz);
#pragma unroll
            for (int r = 0; r < 4; ++r) sAttn[(4 * gq + r) * 20 + lc] = zz[r];
        }

        // deferred THREAD2 for step m-1 (off the W-recurrence chain)
        if (m > 0) {
            f32x4 zbr = *(f32x4*)&sZb[s * 68 + dt * 4];
            float T1 = 0.f, T2 = 0.f;
#pragma unroll
            for (int c = 0; c < 4; ++c) { T1 += zbr[c]; T2 = fmaf(zbr[c], zbr[c], T2); }
            T1 = dpp16(T1); T2 = dpp16(T2);
            const float mu2   = T1 * (1.f / 64.f);
            const float rstd2 = rsqrtf(T2 * (1.f / 64.f) - mu2 * mu2 + 1e-6f);
            const float pqa[4] = {pq_prev.x, pq_prev.y, pq_prev.z, pq_prev.w};
            float o[4];
#pragma unroll
            for (int c = 0; c < 4; ++c)
                o[c] = pqa[c] + fmaf(ga[c], (zbr[c] - mu2) * rstd2, ba[c]);
            const size_t oi = ((size_t)b * 4096 + (size_t)(m - 1) * 16 + s) * 512 + h * 64 + dt * 4;
            *(float4*)&gOUT[oi] = make_float4(o[0], o[1], o[2], o[3]);
        }
        bar();   // (C)

        // ======== THREAD1: LN-bwd (DPP 6-sum) -> g ; stage g^T, xke^T, E ========
        f32x4 z = *(f32x4*)&sZ1[s * 68 + dt * 4];
        float S1=0.f,S2=0.f,S3=0.f,S4=0.f,S5=0.f,S6=0.f;
#pragma unroll
        for (int c = 0; c < 4; ++c) {
            const float zc = z[c], c1z = c1a[c] * zc, t2 = t2c[c];
            S1 += zc;  S2 = fmaf(zc, zc, S2);
            S3 += c1z; S4 = fmaf(c1z, zc, S4);
            S5 += t2;  S6 = fmaf(t2, zc, S6);
        }
        S1 = dpp16(S1); S2 = dpp16(S2); S3 = dpp16(S3);
        S4 = dpp16(S4); S5 = dpp16(S5); S6 = dpp16(S6);
        const float mu   = S1 * (1.f / 64.f);
        const float rstd = rsqrtf(S2 * (1.f / 64.f) - mu * mu + 1e-6f);
        const float r1 = rstd * (S3 - mu * sc1) + S5;
        const float r2 = rstd * rstd * (S4 - 2.f * mu * S3 + mu * mu * sc1)
                       + rstd * (S6 - mu * S5);
        const float cf = rstd * (1.f / 64.f);
        float g[4];
#pragma unroll
        for (int c = 0; c < 4; ++c) {
            const float xh = (z[c] - mu) * rstd;
            const float gx = fmaf(c1a[c], xh, t2c[c]);
            g[c] = (fmaf(64.f, gx, -r1) - xh * r2) * cf;
        }

        const float le = sEta[240 + s];
        const int tb = (s >> 2) * 256 + (dt >> 2) * 64 + (s & 3) * 16 + (dt & 3) * 4;
        { U2S4 gp; gp.u[0]=pkbf(g[0],g[1]); gp.u[1]=pkbf(g[2],g[3]);
          *(short4_t*)&sGt[tb] = gp.s; }
        { U2S4 kp; kp.u[0]=pkbf(-le*pkc.x,-le*pkc.y); kp.u[1]=pkbf(-le*pkc.z,-le*pkc.w);
          *(short4_t*)&sXKe[tb] = kp.s; }

        // E = tril*eta*(1+Attn); store -E
        if (dt < 4) {
            f32x4 at = *(f32x4*)&sAttn[s * 20 + dt * 4];
            f32x4 ev = *(f32x4*)&sEta[s * 16 + dt * 4];
            U2S4 ep;
            float x[4];
#pragma unroll
            for (int c = 0; c < 4; ++c) {
                const int cc = 4 * dt + c;
                x[c] = (cc <= s) ? -ev[c] * (1.f + at[c]) : 0.f;
            }
            ep.u[0] = pkbf(x[0], x[1]); ep.u[1] = pkbf(x[2], x[3]);
            *(short4_t*)&sE[s * 40 + 4 * dt] = ep.s;
        }
        bar();   // (D)

        // ======== MFMA2: Z1_bar, W update (+ b1 partials overlapped) ========
        const unsigned gbase = (unsigned)(size_t)&sGt[0] + 1024u * gq + 8u * lc;
        const unsigned ebase = gbase + 128u * (unsigned)w;
        const unsigned kbase = (unsigned)(size_t)&sXKe[0] + 1024u * gq + 8u * lc
                             + 128u * (unsigned)w;
        short4_t elo, ehi, al, ah;
        short4_t bl0, bh0, bl1, bh1, bl2, bh2, bl3, bh3;
        TR_READ(elo, ebase, "0");   TR_READ(ehi, ebase, "512");
        TR_READ(al,  kbase, "0");   TR_READ(ah,  kbase, "512");
        TR_READ(bl0, gbase, "0");   TR_READ(bh0, gbase, "512");
        TR_READ(bl1, gbase, "128"); TR_READ(bh1, gbase, "640");
        TR_READ(bl2, gbase, "256"); TR_READ(bh2, gbase, "768");
        TR_READ(bl3, gbase, "384"); TR_READ(bh3, gbase, "896");
        const short8 aE = *(const short8*)&sE[lc * 40 + gq * 8];

        // b1 partials (bpermute hops overlap tr-read latency)
        {
            f32x4 bp;
#pragma unroll
            for (int c = 0; c < 4; ++c) {
                float v = le * g[c];
                v += __shfl_xor(v, 16);
                v += __shfl_xor(v, 32);
                bp[c] = v;
            }
            if (gq == 0) *(f32x4*)&sB1p[w * 64 + dt * 4] = bp;
        }
        asm volatile("s_waitcnt lgkmcnt(0)" ::: "memory");
        __builtin_amdgcn_sched_barrier(0);

        f32x4 zb = MFMA32(aE, cmb(elo, ehi), zqa);
#pragma unroll
        for (int r = 0; r < 4; ++r) sZb[(4 * gq + r) * 68 + 16 * w + lc] = zb[r];

        const short8 aK = cmb(al, ah);
        Wacc[0] = MFMA32(aK, cmb(bl0, bh0), Wacc[0]);
        Wacc[1] = MFMA32(aK, cmb(bl1, bh1), Wacc[1]);
        Wacc[2] = MFMA32(aK, cmb(bl2, bh2), Wacc[2]);
        Wacc[3] = MFMA32(aK, cmb(bl3, bh3), Wacc[3]);
#pragma unroll
        for (int ct = 0; ct < 4; ++ct) {
            U2S4 wp;
            wp.u[0] = pkbf(Wacc[ct][0], Wacc[ct][1]);
            wp.u[1] = pkbf(Wacc[ct][2], Wacc[ct][3]);
            *(short4_t*)&sWt[(16 * ct + lc) * 72 + 16 * w + 4 * gq] = wp.s;
        }
        bar();   // (E)

        // b1 state update (cheap; must precede next MFMA1's sB1 read)
        if (t < 64) {
            const float bsum = sB1p[t] + sB1p[64 + t] + sB1p[128 + t] + sB1p[192 + t];
            sB1[t] -= bsum;
        }
        pq_prev = pqc;
    }

    // epilogue: deferred THREAD2 for m = NMB-1
    {
        f32x4 zbr = *(f32x4*)&sZb[s * 68 + dt * 4];
        float T1 = 0.f, T2 = 0.f;
#pragma unroll
        for (int c = 0; c < 4; ++c) { T1 += zbr[c]; T2 = fmaf(zbr[c], zbr[c], T2); }
        T1 = dpp16(T1); T2 = dpp16(T2);
        const float mu2   = T1 * (1.f / 64.f);
        const float rstd2 = rsqrtf(T2 * (1.f / 64.f) - mu2 * mu2 + 1e-6f);
        const float pqa[4] = {pq_prev.x, pq_prev.y, pq_prev.z, pq_prev.w};
        float o[4];
#pragma unroll
        for (int c = 0; c < 4; ++c)
            o[c] = pqa[c] + fmaf(ga[c], (zbr[c] - mu2) * rstd2, ba[c]);
        const size_t oi = ((size_t)b * 4096 + (size_t)(NMB - 1) * 16 + s) * 512 + h * 64 + dt * 4;
        *(float4*)&gOUT[oi] = make_float4(o[0], o[1], o[2], o[3]);
    }
}

extern "C" void kernel_launch(void* const* d_in, const int* in_sizes, int n_in,
                              void* d_out, int out_size, void* d_ws, size_t ws_size,
                              hipStream_t stream) {
    const float* XQ  = (const float*)d_in[0];
    const float* XK  = (const float*)d_in[1];
    const float* XV  = (const float*)d_in[2];
    const float* ETA = (const float*)d_in[3];
    const float* W1  = (const float*)d_in[4];
    const float* B1  = (const float*)d_in[5];
    const float* LNW = (const float*)d_in[6];
    const float* LNB = (const float*)d_in[7];
    float* OUT = (float*)d_out;

    const int n_chains = in_sizes[0] / (NMB * MBS * HD);   // B*nh = 64
    ttt_scan<<<n_chains, 256, 0, stream>>>(XQ, XK, XV, ETA, W1, B1, LNW, LNB, OUT);
}

// Round 8
// 380.230 us; speedup vs baseline: 2.1846x; 1.1976x over previous
//
#include <hip/hip_runtime.h>
#include <hip/hip_bf16.h>

typedef __attribute__((ext_vector_type(8))) short short8;
typedef __attribute__((ext_vector_type(4))) short short4_t;
typedef __attribute__((ext_vector_type(4))) float f32x4;

constexpr int MBS = 16, HD = 64, NMB = 256;

#define MFMA32(a, b, c) __builtin_amdgcn_mfma_f32_16x16x32_bf16(a, b, c, 0, 0, 0)
#define TR_READ(dst, addr, IMM) \
    asm volatile("ds_read_b64_tr_b16 %0, %1 offset:" IMM : "=&v"(dst) : "v"(addr) : "memory")

union U4S8 { unsigned u[4]; short8 s; };
union U2S4 { unsigned u[2]; short4_t s; };
union FI { float f; int i; };

__device__ inline unsigned pkbf(float a, float b) {
    union { __hip_bfloat162 h; unsigned u; } c;
    c.h = __float22bfloat162_rn(make_float2(a, b));
    return c.u;
}
__device__ inline short8 cmb(short4_t a, short4_t b) {
    short8 r;
    r[0]=a[0]; r[1]=a[1]; r[2]=a[2]; r[3]=a[3];
    r[4]=b[0]; r[5]=b[1]; r[6]=b[2]; r[7]=b[3];
    return r;
}
// all-VALU 16-lane sum reduce: quad_perm xor1, xor2, then row_ror 4, 8
__device__ inline float dpp16(float x) {
    FI v; v.f = x; FI t;
    t.i = __builtin_amdgcn_update_dpp(0, v.i, 0xB1, 0xf, 0xf, true);  v.f += t.f;
    t.i = __builtin_amdgcn_update_dpp(0, v.i, 0x4E, 0xf, 0xf, true);  v.f += t.f;
    t.i = __builtin_amdgcn_update_dpp(0, v.i, 0x124, 0xf, 0xf, true); v.f += t.f;
    t.i = __builtin_amdgcn_update_dpp(0, v.i, 0x128, 0xf, 0xf, true); v.f += t.f;
    return v.f;
}
// raw barrier: LDS writes visible, global loads stay in flight
__device__ inline void bar() {
    __builtin_amdgcn_sched_barrier(0);
    asm volatile("s_waitcnt lgkmcnt(0)" ::: "memory");
    __builtin_amdgcn_s_barrier();
    __builtin_amdgcn_sched_barrier(0);
}

__global__ __launch_bounds__(256) void ttt_scan(
    const float* __restrict__ gXQ, const float* __restrict__ gXK,
    const float* __restrict__ gXV, const float* __restrict__ gETA,
    const float* __restrict__ gW1, const float* __restrict__ gB1,
    const float* __restrict__ gLNW, const float* __restrict__ gLNB,
    float* __restrict__ gOUT)
{
    __shared__ __align__(16) short sWt[64 * 72];   // W^T bf16 [n][k], stride 72
    __shared__ __align__(16) short bxk[16 * 72];
    __shared__ __align__(16) short bxq[16 * 72];
    __shared__ __align__(16) short sGt[2048];      // g tiled; jblk 4..7 permanently 0
    __shared__ __align__(16) short sXKe[2048];     // -le*xk tiled; hi jblks 0
    __shared__ __align__(16) short sE[16 * 40];    // -E [r][j], j zero-padded to 32
    __shared__ __align__(16) float sZ1[16 * 68];
    __shared__ __align__(16) float sZb[16 * 68];
    __shared__ __align__(16) float sAttn[16 * 20];
    __shared__ __align__(16) float sEta[2][256];   // parity-buffered (same-phase stage)

    const int t  = threadIdx.x;
    const int s  = t >> 4;
    const int dt = t & 15;
    const int lane = t & 63;
    const int w  = t >> 6;
    const int gq = lane >> 4;
    const int lc = lane & 15;
    const int bh = blockIdx.x, b = bh >> 3, h = bh & 7;

    const float* xqg = gXQ + (size_t)bh * (NMB * MBS * HD);
    const float* xkg = gXK + (size_t)bh * (NMB * MBS * HD);
    const float* xvg = gXV + (size_t)bh * (NMB * MBS * HD);
    const float* etg = gETA + (size_t)bh * (NMB * MBS * MBS);

    for (int i = t; i < 2048; i += 256) { sGt[i] = 0; sXKe[i] = 0; }
    for (int i = t; i < 16 * 40; i += 256) sE[i] = 0;

    // W state: wave w owns rows [16w,16w+16) as 4 C-fragments + bf16 mirror
    f32x4 Wacc[4];
#pragma unroll
    for (int ct = 0; ct < 4; ++ct) {
#pragma unroll
        for (int r = 0; r < 4; ++r)
            Wacc[ct][r] = gW1[h * 4096 + (16 * w + 4 * gq + r) * 64 + 16 * ct + lc];
        U2S4 wp;
        wp.u[0] = pkbf(Wacc[ct][0], Wacc[ct][1]);
        wp.u[1] = pkbf(Wacc[ct][2], Wacc[ct][3]);
        *(short4_t*)&sWt[(16 * ct + lc) * 72 + 16 * w + 4 * gq] = wp.s;
    }
    // b1 state: register, wave w owns col 16w+lc
    float b1v = gB1[h * 64 + 16 * w + lc];

    const float4 gam = *(const float4*)&gLNW[h * 64 + dt * 4];
    const float4 bet = *(const float4*)&gLNB[h * 64 + dt * 4];
    const float ga[4] = {gam.x, gam.y, gam.z, gam.w};
    const float ba[4] = {bet.x, bet.y, bet.z, bet.w};
    float c1a[4], gba[4];
    float sc1 = 0.f;
#pragma unroll
    for (int c = 0; c < 4; ++c) {
        c1a[c] = ga[c] * ga[c];
        gba[c] = ga[c] * ba[c];
        sc1 += c1a[c];
    }
    sc1 = dpp16(sc1);

    const int ecol = (gq < 2) ? 8 * gq : 0;   // aL source columns (clamped)

    // ---- load + stage minibatch 0 ----
    float4 pq = *(const float4*)&xqg[t * 4];
    float4 pk = *(const float4*)&xkg[t * 4];
    float4 pv = *(const float4*)&xvg[t * 4];
    float4 pe = make_float4(0.f, 0.f, 0.f, 0.f);
    if (t < 64) pe = *(const float4*)&etg[t * 4];

    { U2S4 u_; u_.u[0]=pkbf(pk.x,pk.y); u_.u[1]=pkbf(pk.z,pk.w);
      *(short4_t*)&bxk[s * 72 + dt * 4] = u_.s; }
    { U2S4 u_; u_.u[0]=pkbf(pq.x,pq.y); u_.u[1]=pkbf(pq.z,pq.w);
      *(short4_t*)&bxq[s * 72 + dt * 4] = u_.s; }
    if (t < 64) *(float4*)&sEta[0][t * 4] = pe;
    float t2c[4];
    {
        const float pva[4] = {pv.x, pv.y, pv.z, pv.w};
        const float pka_[4] = {pk.x, pk.y, pk.z, pk.w};
#pragma unroll
        for (int c = 0; c < 4; ++c)
            t2c[c] = fmaf(-ga[c], pva[c] - pka_[c], gba[c]);
    }
    float4 pkc = pk;        // xk(m) for THREAD1's sXKe
    float4 pq_out = pq;     // xq(m) for THREAD2(m)
    float4 pq_prev_out;     // xq(m-1) for deferred THREAD2

    __syncthreads();

#pragma unroll 1
    for (int m = 0; m < NMB; ++m) {
        const int p = m & 1;

        // ======== PHASE A: MFMA1 (+ deferred THREAD2 of m-1; prefetch m+1) ========
        if (m + 1 < NMB) {
            const size_t o = (size_t)(m + 1) * (MBS * HD) + t * 4;
            pq = *(const float4*)&xqg[o];
            pk = *(const float4*)&xkg[o];
            pv = *(const float4*)&xvg[o];
            if (t < 64) pe = *(const float4*)&etg[(size_t)(m + 1) * (MBS * MBS) + t * 4];
        }

        f32x4 z1a; z1a[0]=b1v; z1a[1]=b1v; z1a[2]=b1v; z1a[3]=b1v;
        f32x4 zqa = z1a;
        const short8 ak0 = *(const short8*)&bxk[lc * 72 + gq * 8];
        const short8 ak1 = *(const short8*)&bxk[lc * 72 + gq * 8 + 32];
        const short8 aq0 = *(const short8*)&bxq[lc * 72 + gq * 8];
        const short8 aq1 = *(const short8*)&bxq[lc * 72 + gq * 8 + 32];
        const short8 bw0 = *(const short8*)&sWt[(16 * w + lc) * 72 + gq * 8];
        const short8 bw1 = *(const short8*)&sWt[(16 * w + lc) * 72 + gq * 8 + 32];
        z1a = MFMA32(ak0, bw0, z1a); z1a = MFMA32(ak1, bw1, z1a);
        zqa = MFMA32(aq0, bw0, zqa); zqa = MFMA32(aq1, bw1, zqa);
#pragma unroll
        for (int r = 0; r < 4; ++r) sZ1[(4 * gq + r) * 68 + 16 * w + lc] = z1a[r];
        if (w == 3) {
            f32x4 zz; zz[0]=0.f; zz[1]=0.f; zz[2]=0.f; zz[3]=0.f;
            zz = MFMA32(aq0, ak0, zz); zz = MFMA32(aq1, ak1, zz);
#pragma unroll
            for (int r = 0; r < 4; ++r) sAttn[(4 * gq + r) * 20 + lc] = zz[r];
        }

        // deferred THREAD2 for step m-1 (off the W-recurrence chain)
        if (m > 0) {
            f32x4 zbr = *(f32x4*)&sZb[s * 68 + dt * 4];
            float T1 = 0.f, T2 = 0.f;
#pragma unroll
            for (int c = 0; c < 4; ++c) { T1 += zbr[c]; T2 = fmaf(zbr[c], zbr[c], T2); }
            T1 = dpp16(T1); T2 = dpp16(T2);
            const float mu2   = T1 * (1.f / 64.f);
            const float rstd2 = rsqrtf(T2 * (1.f / 64.f) - mu2 * mu2 + 1e-6f);
            const float pqa[4] = {pq_prev_out.x, pq_prev_out.y, pq_prev_out.z, pq_prev_out.w};
            float o[4];
#pragma unroll
            for (int c = 0; c < 4; ++c)
                o[c] = pqa[c] + fmaf(ga[c], (zbr[c] - mu2) * rstd2, ba[c]);
            const size_t oi = ((size_t)b * 4096 + (size_t)(m - 1) * 16 + s) * 512 + h * 64 + dt * 4;
            *(float4*)&gOUT[oi] = make_float4(o[0], o[1], o[2], o[3]);
        }
        bar();   // (C)

        // ======== PHASE B: THREAD1 — LN-bwd (DPP 6-sum) -> g ; stage g^T, xke^T, E ====
        f32x4 z = *(f32x4*)&sZ1[s * 68 + dt * 4];
        float S1=0.f,S2=0.f,S3=0.f,S4=0.f,S5=0.f,S6=0.f;
#pragma unroll
        for (int c = 0; c < 4; ++c) {
            const float zc = z[c], c1z = c1a[c] * zc, t2 = t2c[c];
            S1 += zc;  S2 = fmaf(zc, zc, S2);
            S3 += c1z; S4 = fmaf(c1z, zc, S4);
            S5 += t2;  S6 = fmaf(t2, zc, S6);
        }
        S1 = dpp16(S1); S2 = dpp16(S2); S3 = dpp16(S3);
        S4 = dpp16(S4); S5 = dpp16(S5); S6 = dpp16(S6);
        const float mu   = S1 * (1.f / 64.f);
        const float rstd = rsqrtf(S2 * (1.f / 64.f) - mu * mu + 1e-6f);
        const float r1 = rstd * (S3 - mu * sc1) + S5;
        const float r2 = rstd * rstd * (S4 - 2.f * mu * S3 + mu * mu * sc1)
                       + rstd * (S6 - mu * S5);
        const float cf = rstd * (1.f / 64.f);
        float g[4];
#pragma unroll
        for (int c = 0; c < 4; ++c) {
            const float xh = (z[c] - mu) * rstd;
            const float gx = fmaf(c1a[c], xh, t2c[c]);
            g[c] = (fmaf(64.f, gx, -r1) - xh * r2) * cf;
        }

        const float le = sEta[p][240 + s];
        const int tb = (s >> 2) * 256 + (dt >> 2) * 64 + (s & 3) * 16 + (dt & 3) * 4;
        { U2S4 gp; gp.u[0]=pkbf(g[0],g[1]); gp.u[1]=pkbf(g[2],g[3]);
          *(short4_t*)&sGt[tb] = gp.s; }
        { U2S4 kp; kp.u[0]=pkbf(-le*pkc.x,-le*pkc.y); kp.u[1]=pkbf(-le*pkc.z,-le*pkc.w);
          *(short4_t*)&sXKe[tb] = kp.s; }

        // E = tril*eta*(1+Attn); store -E
        if (dt < 4) {
            f32x4 at = *(f32x4*)&sAttn[s * 20 + dt * 4];
            f32x4 ev = *(f32x4*)&sEta[p][s * 16 + dt * 4];
            U2S4 ep;
            float x[4];
#pragma unroll
            for (int c = 0; c < 4; ++c) {
                const int cc = 4 * dt + c;
                x[c] = (cc <= s) ? -ev[c] * (1.f + at[c]) : 0.f;
            }
            ep.u[0] = pkbf(x[0], x[1]); ep.u[1] = pkbf(x[2], x[3]);
            *(short4_t*)&sE[s * 40 + 4 * dt] = ep.s;
        }
        bar();   // (D)

        // ======== PHASE C: MFMA2 (Z1_bar, W, b1) + STAGE(m+1) ========
        const unsigned gbase = (unsigned)(size_t)&sGt[0] + 1024u * gq + 8u * lc;
        const unsigned ebase = gbase + 128u * (unsigned)w;
        const unsigned kbase = (unsigned)(size_t)&sXKe[0] + 1024u * gq + 8u * lc
                             + 128u * (unsigned)w;
        short4_t elo, ehi, al, ah;
        short4_t bl0, bh0, bl1, bh1, bl2, bh2, bl3, bh3;
        TR_READ(elo, ebase, "0");   TR_READ(ehi, ebase, "512");
        TR_READ(al,  kbase, "0");   TR_READ(ah,  kbase, "512");
        TR_READ(bl0, gbase, "0");   TR_READ(bh0, gbase, "512");
        TR_READ(bl1, gbase, "128"); TR_READ(bh1, gbase, "640");
        TR_READ(bl2, gbase, "256"); TR_READ(bh2, gbase, "768");
        TR_READ(bl3, gbase, "384"); TR_READ(bh3, gbase, "896");
        const short8 aE = *(const short8*)&sE[lc * 40 + gq * 8];
        // aL: A[row][k] = -le[k] (k<16; zero for gq>=2), from current step's eta
        const f32x4 le0 = *(const f32x4*)&sEta[p][240 + ecol];
        const f32x4 le1 = *(const f32x4*)&sEta[p][244 + ecol];
        U4S8 aL;
        {
            const float lv[8] = {le0[0], le0[1], le0[2], le0[3], le1[0], le1[1], le1[2], le1[3]};
#pragma unroll
            for (int pp = 0; pp < 4; ++pp) {
                const float y0 = (gq < 2) ? -lv[2 * pp] : 0.f;
                const float y1 = (gq < 2) ? -lv[2 * pp + 1] : 0.f;
                aL.u[pp] = pkbf(y0, y1);
            }
        }
        asm volatile("s_waitcnt lgkmcnt(0)" ::: "memory");
        __builtin_amdgcn_sched_barrier(0);

        const short8 bgw = cmb(elo, ehi);
        f32x4 zb = MFMA32(aE, bgw, zqa);
#pragma unroll
        for (int r = 0; r < 4; ++r) sZb[(4 * gq + r) * 68 + 16 * w + lc] = zb[r];

        const short8 aK = cmb(al, ah);
        Wacc[0] = MFMA32(aK, cmb(bl0, bh0), Wacc[0]);
        Wacc[1] = MFMA32(aK, cmb(bl1, bh1), Wacc[1]);
        Wacc[2] = MFMA32(aK, cmb(bl2, bh2), Wacc[2]);
        Wacc[3] = MFMA32(aK, cmb(bl3, bh3), Wacc[3]);
        // b1 update: d0 = (-le) @ g  (same B-frag as zb)
        {
            f32x4 d0; d0[0]=0.f; d0[1]=0.f; d0[2]=0.f; d0[3]=0.f;
            d0 = MFMA32(aL.s, bgw, d0);
            b1v += d0[0];
        }
#pragma unroll
        for (int ct = 0; ct < 4; ++ct) {
            U2S4 wp;
            wp.u[0] = pkbf(Wacc[ct][0], Wacc[ct][1]);
            wp.u[1] = pkbf(Wacc[ct][2], Wacc[ct][3]);
            *(short4_t*)&sWt[(16 * ct + lc) * 72 + 16 * w + 4 * gq] = wp.s;
        }

        // STAGE(m+1): bxk/bxq/sEta[p^1]/t2 from prefetched regs (buffers dead since bar D)
        if (m + 1 < NMB) {
            { U2S4 u_; u_.u[0]=pkbf(pk.x,pk.y); u_.u[1]=pkbf(pk.z,pk.w);
              *(short4_t*)&bxk[s * 72 + dt * 4] = u_.s; }
            { U2S4 u_; u_.u[0]=pkbf(pq.x,pq.y); u_.u[1]=pkbf(pq.z,pq.w);
              *(short4_t*)&bxq[s * 72 + dt * 4] = u_.s; }
            if (t < 64) *(float4*)&sEta[p ^ 1][t * 4] = pe;
#pragma unroll
            for (int c = 0; c < 4; ++c) {
                const float pva[4] = {pv.x, pv.y, pv.z, pv.w};
                const float pka_[4] = {pk.x, pk.y, pk.z, pk.w};
                t2c[c] = fmaf(-ga[c], pva[c] - pka_[c], gba[c]);
            }
            pkc = pk;
        }
        pq_prev_out = pq_out;
        pq_out = pq;
        bar();   // (E)
    }

    // epilogue: deferred THREAD2 for m = NMB-1
    {
        f32x4 zbr = *(f32x4*)&sZb[s * 68 + dt * 4];
        float T1 = 0.f, T2 = 0.f;
#pragma unroll
        for (int c = 0; c < 4; ++c) { T1 += zbr[c]; T2 = fmaf(zbr[c], zbr[c], T2); }
        T1 = dpp16(T1); T2 = dpp16(T2);
        const float mu2   = T1 * (1.f / 64.f);
        const float rstd2 = rsqrtf(T2 * (1.f / 64.f) - mu2 * mu2 + 1e-6f);
        const float pqa[4] = {pq_prev_out.x, pq_prev_out.y, pq_prev_out.z, pq_prev_out.w};
        float o[4];
#pragma unroll
        for (int c = 0; c < 4; ++c)
            o[c] = pqa[c] + fmaf(ga[c], (zbr[c] - mu2) * rstd2, ba[c]);
        const size_t oi = ((size_t)b * 4096 + (size_t)(NMB - 1) * 16 + s) * 512 + h * 64 + dt * 4;
        *(float4*)&gOUT[oi] = make_float4(o[0], o[1], o[2], o[3]);
    }
}

extern "C" void kernel_launch(void* const* d_in, const int* in_sizes, int n_in,
                              void* d_out, int out_size, void* d_ws, size_t ws_size,
                              hipStream_t stream) {
    const float* XQ  = (const float*)d_in[0];
    const float* XK  = (const float*)d_in[1];
    const float* XV  = (const float*)d_in[2];
    const float* ETA = (const float*)d_in[3];
    const float* W1  = (const float*)d_in[4];
    const float* B1  = (const float*)d_in[5];
    const float* LNW = (const float*)d_in[6];
    const float* LNB = (const float*)d_in[7];
    float* OUT = (float*)d_out;

    const int n_chains = in_sizes[0] / (NMB * MBS * HD);   // B*nh = 64
    ttt_scan<<<n_chains, 256, 0, stream>>>(XQ, XK, XV, ETA, W1, B1, LNW, LNB, OUT);
}